// Round 5
// baseline (351.577 us; speedup 1.0000x reference)
//
#include <hip/hip_runtime.h>

#define B 8
#define N 2048
#define D 1024
#define C 32            // chunks along i
#define LC (N / C)      // 64 rows per chunk
#define M 6             // Taylor terms
#define DQ 4            // D-slices per chunk
#define COLS (D / DQ)   // 256 cols per block
#define NBLK (B * C * DQ)   // 1024 blocks
#define TPB 256
#define RECF (M * COLS)     // 1536 floats per aggregate record

// Flags live in __device__ globals (NOT in the poisoned workspace).
// Epoch protocol: per launch, every block derives the same epoch from a
// monotone counter; a flag is "set" iff it equals the current epoch, so
// stale values from previous replays/poison are never trusted and no
// reset dispatch is needed. Launches are stream-serialized, so all 1024
// increments of launch L complete before launch L+1 starts.
__device__ unsigned g_ctr;          // zero-init at module load
__device__ int g_flagP[B * C * DQ]; // proj rows done, idx ((b*C+c)*DQ+dq)
__device__ int g_flagA[B * DQ * C]; // aggregate done, idx (chain*C+c), chain=b*DQ+dq

// ws layout (floats):
//   kq    @ 0     : 2*B*N = 32768 (k then q)
//   precs @ 32768 : 1024 records x RECF = 1572864 floats (~6 MB)

__global__ __launch_bounds__(TPB, 4) void k_all(
    const float* __restrict__ x, const float* __restrict__ f,
    const float* __restrict__ wk, const float* __restrict__ wq,
    float* __restrict__ kq, float* __restrict__ precs,
    float* __restrict__ out)
{
    const int bid   = blockIdx.x;
    const int dq    = bid & (DQ - 1);
    const int c     = (bid >> 2) & (C - 1);
    const int b     = bid >> 7;
    const int chain = b * DQ + dq;                 // 0..31
    const int tid   = threadIdx.x;
    const int wave  = tid >> 6;
    const int lane  = tid & 63;

    __shared__ float sk[LC];
    __shared__ float sq[LC];
    __shared__ float sT[M];
    __shared__ int   s_ep;

    if (tid == 0) s_ep = (int)(atomicAdd(&g_ctr, 1u) / NBLK) + 1;
    __syncthreads();
    const int ep = s_ep;

    // ---- P0: projection for this block's 16 rows (rows partitioned by dq,
    //          so x is read exactly once across the grid). 4 rows per wave.
    {
        const float4* wk4 = (const float4*)wk;
        const float4* wq4 = (const float4*)wq;
        float4 kw[4], qw[4];
#pragma unroll
        for (int t = 0; t < 4; ++t) { kw[t] = wk4[t * 64 + lane]; qw[t] = wq4[t * 64 + lane]; }
#pragma unroll
        for (int r = 0; r < 4; ++r) {
            const int row = c * LC + dq * 16 + wave * 4 + r;   // within batch b
            const float4* xr = (const float4*)(x + ((size_t)(b * N + row)) * D);
            float ak = 0.f, aq = 0.f;
#pragma unroll
            for (int t = 0; t < 4; ++t) {
                float4 xv = xr[t * 64 + lane];
                ak += xv.x * kw[t].x + xv.y * kw[t].y + xv.z * kw[t].z + xv.w * kw[t].w;
                aq += xv.x * qw[t].x + xv.y * qw[t].y + xv.z * qw[t].z + xv.w * qw[t].w;
            }
#pragma unroll
            for (int off = 32; off > 0; off >>= 1) {
                ak += __shfl_down(ak, off, 64);
                aq += __shfl_down(aq, off, 64);
            }
            if (lane == 0) {
                kq[b * N + row] = ak;
                kq[B * N + b * N + row] = aq;
            }
        }
    }
    __syncthreads();                               // drains stores before fence
    if (tid == 0) {
        __threadfence();
        __hip_atomic_store(&g_flagP[(b * C + c) * DQ + dq], ep,
                           __ATOMIC_RELAXED, __HIP_MEMORY_SCOPE_AGENT);
    }

    // ---- P1: wait for own chunk's 4 proj slices; load sk/sq
    if (tid < DQ) {
        while (__hip_atomic_load(&g_flagP[(b * C + c) * DQ + tid],
                                 __ATOMIC_RELAXED, __HIP_MEMORY_SCOPE_AGENT) != ep)
            __builtin_amdgcn_s_sleep(2);
    }
    __syncthreads();
    (void)__hip_atomic_load(&g_flagP[(b * C + c) * DQ],
                            __ATOMIC_ACQUIRE, __HIP_MEMORY_SCOPE_AGENT);
    if (tid < LC)            sk[tid]      = kq[b * N + c * LC + tid];
    else if (tid < 2 * LC)   sq[tid - LC] = kq[B * N + b * N + c * LC + (tid - LC)];
    __syncthreads();

    // ---- P2: vector chunk moments; thread owns one column d
    const int d = dq * COLS + tid;
    const float* fb = f + ((size_t)(b * N + c * LC)) * D + d;
    float s[M] = {0.f, 0.f, 0.f, 0.f, 0.f, 0.f};
#pragma unroll 8
    for (int i = 0; i < LC; ++i) {
        float ff = fb[(size_t)i * D];
        float kk = sk[i];
        float w  = (kk != 0.0f) ? 1.0f : 0.0f;
        s[0] += w * ff;
        float kp = kk;
#pragma unroll
        for (int m = 1; m < M; ++m) { s[m] += kp * ff; kp *= kk; }
    }

    // ---- P3: publish aggregate record (last chunk has no successor)
    if (c < C - 1) {
        float* rec = precs + (size_t)(chain * C + c) * RECF;
#pragma unroll
        for (int m = 0; m < M; ++m) rec[m * COLS + tid] = s[m];
        __syncthreads();
        if (tid == 0) {
            __threadfence();
            __hip_atomic_store(&g_flagA[chain * C + c], ep,
                               __ATOMIC_RELAXED, __HIP_MEMORY_SCOPE_AGENT);
        }
    }

    // ---- P4/P5 spins: all proj slices of batch b (for the scalar prefix),
    //      then this chain's predecessor aggregates. Both publish chains are
    //      spin-free upstream -> acyclic -> deadlock-free (all blocks resident).
    if (tid < C * DQ) {                            // 128 flags of batch b
        while (__hip_atomic_load(&g_flagP[b * C * DQ + tid],
                                 __ATOMIC_RELAXED, __HIP_MEMORY_SCOPE_AGENT) != ep)
            __builtin_amdgcn_s_sleep(2);
    }
    if (tid < c) {
        while (__hip_atomic_load(&g_flagA[chain * C + tid],
                                 __ATOMIC_RELAXED, __HIP_MEMORY_SCOPE_AGENT) != ep)
            __builtin_amdgcn_s_sleep(2);
    }
    __syncthreads();
    (void)__hip_atomic_load(&g_flagP[b * C * DQ],
                            __ATOMIC_ACQUIRE, __HIP_MEMORY_SCOPE_AGENT);

    // ---- P4b: scalar exclusive prefix over chunks (lanes 0..31 of wave 0)
    if (tid < C) {
        float tm[M] = {0.f, 0.f, 0.f, 0.f, 0.f, 0.f};
        const float* kb = kq + b * N + tid * LC;
#pragma unroll 8
        for (int i = 0; i < LC; ++i) {
            float kk = kb[i];
            tm[0] += (kk != 0.0f) ? 1.0f : 0.0f;
            float kp = kk;
#pragma unroll
            for (int m = 1; m < M; ++m) { tm[m] += kp; kp *= kk; }
        }
#pragma unroll
        for (int m = 0; m < M; ++m) {
            float v = tm[m];
            const float orig = v;
#pragma unroll
            for (int off = 1; off < C; off <<= 1) {    // Kogge-Stone, 32 lanes
                float nv = __shfl_up(v, off, 64);
                if (tid >= off) v += nv;
            }
            if (tid == c) sT[m] = v - orig;            // exclusive prefix @ c
        }
    }

    // ---- P5b: bounded lookback, forward order (same association as scan)
    float run[M] = {0.f, 0.f, 0.f, 0.f, 0.f, 0.f};
#pragma unroll 1
    for (int p = 0; p < c; ++p) {
        const float* rp = precs + (size_t)(chain * C + p) * RECF;
#pragma unroll
        for (int m = 0; m < M; ++m) run[m] += rp[m * COLS + tid];
    }
    __syncthreads();                               // sT visible to all waves

    float t[M];
#pragma unroll
    for (int m = 0; m < M; ++m) t[m] = sT[m];

    // ---- P6: local scan + Horner + output (f re-read is L2/L3-warm)
    float* ob = out + ((size_t)(b * N + c * LC)) * D + d;
#pragma unroll 4
    for (int i = 0; i < LC; ++i) {
        float ff = fb[(size_t)i * D];
        float kk = sk[i];
        float qq = sq[i];
        float w  = (kk != 0.0f) ? 1.0f : 0.0f;
        t[0] += w;
        run[0] += w * ff;
        float kp = kk;
#pragma unroll
        for (int m = 1; m < M; ++m) {
            t[m] += kp;
            run[m] += kp * ff;
            kp *= kk;
        }
        const float cj = qq * 0.03125f;
        const float g2 = cj * 0.5f;
        const float g3 = cj * (1.0f / 3.0f);
        const float g4 = cj * 0.25f;
        const float g5 = cj * 0.2f;
        float Z = ((((t[5] * g5 + t[4]) * g4 + t[3]) * g3 + t[2]) * g2 + t[1]) * cj + t[0];
        float rz = __builtin_amdgcn_rcpf(Z);
        ob[(size_t)i * D] =
            (((((run[5] * g5 + run[4]) * g4 + run[3]) * g3 + run[2]) * g2 + run[1]) * cj + run[0]) * rz;
    }
}

// ---------------------------------------------------------------------------
extern "C" void kernel_launch(void* const* d_in, const int* in_sizes, int n_in,
                              void* d_out, int out_size, void* d_ws, size_t ws_size,
                              hipStream_t stream) {
    (void)in_sizes; (void)n_in; (void)out_size; (void)ws_size;
    const float* x  = (const float*)d_in[0];
    const float* f  = (const float*)d_in[1];
    const float* wk = (const float*)d_in[2];
    const float* wq = (const float*)d_in[3];
    float* out = (float*)d_out;
    float* ws  = (float*)d_ws;

    float* kq    = ws;
    float* precs = ws + 32768;

    hipLaunchKernelGGL(k_all, dim3(NBLK), dim3(TPB), 0, stream,
                       x, f, wk, wq, kq, precs, out);
}

// Round 6
// 196.795 us; speedup vs baseline: 1.7865x; 1.7865x over previous
//
#include <hip/hip_runtime.h>

#define B 8
#define N 2048
#define D 1024
#define SC 64          // subchunks along i
#define LC (N / SC)    // 32 rows per subchunk
#define M 6            // Taylor terms

// ws layout (floats):
//   kq   @ 0     : 2*B*N = 32768   (k then q)
//   part @ 65536 : B*SC*M*D = 3145728 floats (~12.6 MB)

// ---------------------------------------------------------------------------
// K1: fused projection + partial moments. Block = (b, sc), 256 threads.
//     Granularity matching makes the block self-sufficient: it projects its
//     own 32 rows (k kept in LDS, k/q also written to kq for K3), then
//     accumulates the chunk moments — no inter-block dependency, no sync.
__global__ __launch_bounds__(256) void k_pp(const float* __restrict__ x,
                                            const float* __restrict__ f,
                                            const float* __restrict__ wk,
                                            const float* __restrict__ wq,
                                            float* __restrict__ kq,
                                            float* __restrict__ part) {
    const int sc   = blockIdx.x & (SC - 1);
    const int b    = blockIdx.x >> 6;
    const int tid  = threadIdx.x;
    const int wave = tid >> 6;
    const int lane = tid & 63;

    __shared__ float sk[LC];

    // ---- projection: 8 rows per wave, wave64 dot per row (same op order
    //      as the proven k_proj: float4 tiles, lane-strided, shfl reduce)
    {
        const float4* wk4 = (const float4*)wk;
        const float4* wq4 = (const float4*)wq;
        float4 kw[4], qw[4];
#pragma unroll
        for (int t = 0; t < 4; ++t) { kw[t] = wk4[t * 64 + lane]; qw[t] = wq4[t * 64 + lane]; }
#pragma unroll
        for (int r = 0; r < 8; ++r) {
            const int rl  = wave * 8 + r;                  // local row 0..31
            const int row = b * N + sc * LC + rl;
            const float4* xr = (const float4*)(x + (size_t)row * D);
            float ak = 0.f, aq = 0.f;
#pragma unroll
            for (int t = 0; t < 4; ++t) {
                float4 xv = xr[t * 64 + lane];
                ak += xv.x * kw[t].x + xv.y * kw[t].y + xv.z * kw[t].z + xv.w * kw[t].w;
                aq += xv.x * qw[t].x + xv.y * qw[t].y + xv.z * qw[t].z + xv.w * qw[t].w;
            }
#pragma unroll
            for (int off = 32; off > 0; off >>= 1) {
                ak += __shfl_down(ak, off, 64);
                aq += __shfl_down(aq, off, 64);
            }
            if (lane == 0) {
                sk[rl] = ak;                               // local use (moments)
                kq[row] = ak;                              // K3: scalar prefix
                kq[B * N + row] = aq;                      // K3: Horner coeff
            }
        }
    }
    __syncthreads();

    // ---- partial moments: thread owns one float4 column (k_part verbatim)
    const float4* fb = (const float4*)(f + (size_t)(b * N + sc * LC) * D) + tid;
    float4 s[M];
#pragma unroll
    for (int m = 0; m < M; ++m) s[m] = make_float4(0.f, 0.f, 0.f, 0.f);
#pragma unroll 8
    for (int i = 0; i < LC; ++i) {
        float4 ff = fb[i * (D / 4)];
        float  kk = sk[i];
        float  w  = (kk != 0.0f) ? 1.0f : 0.0f;
        s[0].x += w * ff.x; s[0].y += w * ff.y; s[0].z += w * ff.z; s[0].w += w * ff.w;
        float kp = kk;
#pragma unroll
        for (int m = 1; m < M; ++m) {
            s[m].x += kp * ff.x; s[m].y += kp * ff.y;
            s[m].z += kp * ff.z; s[m].w += kp * ff.w;
            kp *= kk;
        }
    }
    float4* pb = (float4*)(part + (size_t)(b * SC + sc) * M * D) + tid;
#pragma unroll
    for (int m = 0; m < M; ++m) pb[m * (D / 4)] = s[m];
}

// ---------------------------------------------------------------------------
// K2: in-place exclusive scan of part over sc (R3 verbatim). One float column
//     per thread: B*M*D = 49152 threads = 192 blocks; record stride M*D.
__global__ __launch_bounds__(256) void k_scan(float* __restrict__ part) {
    const int gid  = blockIdx.x * 256 + threadIdx.x;   // [0, B*M*D)
    const int d    = gid & (D - 1);
    const int rest = gid >> 10;                        // [0, 48)
    const int m    = rest % M;
    const int b    = rest / M;
    const size_t base = ((size_t)(b * SC) * M + m) * D + d;
    const size_t cs   = (size_t)M * D;                 // floats per record
    float run = 0.f;
#pragma unroll 1
    for (int c0 = 0; c0 < SC; c0 += 8) {
        float buf[8];
#pragma unroll
        for (int j = 0; j < 8; ++j) buf[j] = part[base + (size_t)(c0 + j) * cs];
#pragma unroll
        for (int j = 0; j < 8; ++j) {
            float v = buf[j];
            part[base + (size_t)(c0 + j) * cs] = run;
            run += v;
        }
    }
}

// ---------------------------------------------------------------------------
// K3: output (R3 verbatim). Block = (b, sc), 256 threads. Wave 0 recomputes
//     the scalar exclusive prefix bit-identically (lane = subchunk, 32-row
//     serial partials + Kogge-Stone shfl_up, take lane sc).
__global__ __launch_bounds__(256) void k_out(const float* __restrict__ kq,
                                             const float* __restrict__ f,
                                             const float* __restrict__ part,
                                             float* __restrict__ out) {
    const int sc  = blockIdx.x & (SC - 1);
    const int b   = blockIdx.x >> 6;
    const int tid = threadIdx.x;

    __shared__ float sk[LC];
    __shared__ float sq[LC];
    __shared__ float sT[M];

    if (tid < 64) {
        float tm[M] = {0.f, 0.f, 0.f, 0.f, 0.f, 0.f};
        const float* kb = kq + b * N + tid * LC;
#pragma unroll
        for (int i = 0; i < LC; ++i) {
            float kk = kb[i];
            tm[0] += (kk != 0.0f) ? 1.0f : 0.0f;
            float kp = kk;
#pragma unroll
            for (int m = 1; m < M; ++m) { tm[m] += kp; kp *= kk; }
        }
#pragma unroll
        for (int m = 0; m < M; ++m) {
            float v = tm[m];
            const float orig = v;
#pragma unroll
            for (int off = 1; off < 64; off <<= 1) {
                float nv = __shfl_up(v, off, 64);
                if (tid >= off) v += nv;
            }
            if (tid == sc) sT[m] = v - orig;           // exclusive prefix @ sc
        }
    } else if (tid < 64 + LC) {
        sk[tid - 64] = kq[b * N + sc * LC + (tid - 64)];
    } else if (tid >= 128 && tid < 128 + LC) {
        sq[tid - 128] = kq[B * N + b * N + sc * LC + (tid - 128)];
    }
    __syncthreads();

    float4 s[M];
    float  t[M];
    const float4* pb = (const float4*)(part + (size_t)(b * SC + sc) * M * D) + tid;
#pragma unroll
    for (int m = 0; m < M; ++m) s[m] = pb[m * (D / 4)];
#pragma unroll
    for (int m = 0; m < M; ++m) t[m] = sT[m];

    const float4* fb = (const float4*)(f + (size_t)(b * N + sc * LC) * D) + tid;
    float4*       ob = (float4*)(out + (size_t)(b * N + sc * LC) * D) + tid;

#pragma unroll 4
    for (int i = 0; i < LC; ++i) {
        float4 ff = fb[i * (D / 4)];
        float  kk = sk[i];
        float  qq = sq[i];
        float  w  = (kk != 0.0f) ? 1.0f : 0.0f;
        t[0] += w;
        s[0].x += w * ff.x; s[0].y += w * ff.y; s[0].z += w * ff.z; s[0].w += w * ff.w;
        float kp = kk;
#pragma unroll
        for (int m = 1; m < M; ++m) {
            t[m] += kp;
            s[m].x += kp * ff.x; s[m].y += kp * ff.y;
            s[m].z += kp * ff.z; s[m].w += kp * ff.w;
            kp *= kk;
        }
        const float cj = qq * 0.03125f;
        const float g2 = cj * 0.5f;
        const float g3 = cj * (1.0f / 3.0f);
        const float g4 = cj * 0.25f;
        const float g5 = cj * 0.2f;
        float Z = ((((t[5] * g5 + t[4]) * g4 + t[3]) * g3 + t[2]) * g2 + t[1]) * cj + t[0];
        float rz = __builtin_amdgcn_rcpf(Z);
        float4 o;
        o.x = (((((s[5].x * g5 + s[4].x) * g4 + s[3].x) * g3 + s[2].x) * g2 + s[1].x) * cj + s[0].x) * rz;
        o.y = (((((s[5].y * g5 + s[4].y) * g4 + s[3].y) * g3 + s[2].y) * g2 + s[1].y) * cj + s[0].y) * rz;
        o.z = (((((s[5].z * g5 + s[4].z) * g4 + s[3].z) * g3 + s[2].z) * g2 + s[1].z) * cj + s[0].z) * rz;
        o.w = (((((s[5].w * g5 + s[4].w) * g4 + s[3].w) * g3 + s[2].w) * g2 + s[1].w) * cj + s[0].w) * rz;
        ob[i * (D / 4)] = o;
    }
}

// ---------------------------------------------------------------------------
extern "C" void kernel_launch(void* const* d_in, const int* in_sizes, int n_in,
                              void* d_out, int out_size, void* d_ws, size_t ws_size,
                              hipStream_t stream) {
    (void)in_sizes; (void)n_in; (void)out_size; (void)ws_size;
    const float* x  = (const float*)d_in[0];
    const float* f  = (const float*)d_in[1];
    const float* wk = (const float*)d_in[2];
    const float* wq = (const float*)d_in[3];
    float* out = (float*)d_out;
    float* ws  = (float*)d_ws;

    float* kq   = ws;
    float* part = ws + 65536;

    hipLaunchKernelGGL(k_pp,   dim3(B * SC),           dim3(256), 0, stream, x, f, wk, wq, kq, part);
    hipLaunchKernelGGL(k_scan, dim3(B * M * D / 256),  dim3(256), 0, stream, part);
    hipLaunchKernelGGL(k_out,  dim3(B * SC),           dim3(256), 0, stream, kq, f, part, out);
}